// Round 5
// baseline (404.125 us; speedup 1.0000x reference)
//
#include <hip/hip_runtime.h>

// ErosionLayer: B=16, W=512, ITERS=10, fp32. PASSING numeric recipe (r5..r13,
// absmax 0.02734375): XLA-style greedy FMA via explicit fmaf() at exact sites,
// contract(off) elsewhere, correctly-rounded fp32 div/sqrt. cell_math op order
// is the frozen recipe -- only PROVABLY bit-exact simplifications allowed.
//
// r17 PASSED 353.6us: ping-pong dbuf of s/w/v across dispatches kills the
// inter-block race (r15/r16 failures). HH=4, 21 waves/CU avg -> 94-98% busy.
// r18 PASSED 322.6us: bit-exact DCE (factor==0 => rY/den dead) + HH=8
// (recompute ratio 1.25 vs 1.5). But 56 KiB LDS -> 2 blocks/CU -> Occ 32%,
// VALUBusy 77%: latency-limited again. Busy-vs-waves: 6.5w->58%, 10w->77%,
// 21w->96%.
//
// r19 (this round): LDS ALIASING -> full occupancy at HH=8's work ratio.
// During phase 1, A slot i (terrain k-1 row r0-4+i) is dead once B row i
// (terrain-k row r0-2+i) is computed: row x reads exactly slots i..i+4
// (y0c >= x-2 -> ty0 >= i; y1c <= x+2 -> ty1 <= i+4, incl. clamps).
// So: compute a PAIR of B rows into regs -> __syncthreads -> write into
// slots i,i+1 (next pair reads i+2..i+7, untouched). B buffer eliminated:
// LDS 56 -> 32 KiB, 4 blocks/CU (128 KiB, 32 waves = 100% theoretical),
// grid 1024 = exactly ONE residency round. Phase 2 reads terrain-k from the
// same array with rowOfs r0-2 (slot j = row r0-2+j); clamping keeps stale
// slots (12..15, and 0..1 at r0=0) unread -- verified r0 in {0,504}.
// 7 extra barriers/dispatch, amortized by 4 independent blocks/CU.
// __launch_bounds__(512,8) caps VGPR at 64 (r18 natural 52). Inter-dispatch
// s/w/v dbuf unchanged. Bit-exact vs r18. FINAL skips dead s/w/v stores.
#pragma clang fp contract(off)

constexpr int WW   = 512;
constexpr int NPIX = WW * WW;      // 2^18
constexpr int NTOT = 16 * NPIX;    // 4194304
constexpr int HH   = 8;            // owned rows per block
constexpr int AR   = 16;           // LDS rows [r0-4, r0+11]; B aliased in
constexpr int BR   = 12;           // phase-1 computed rows [r0-2, r0+9]
constexpr int NBLK = 16 * (WW / HH);   // 1024

// FROZEN r5/r6 math (+ r18 provably-bit-exact factor/rY/den removal);
// all terrain reads from an LDS tile with row offset.
__device__ __forceinline__ void cell_math(
    const float* __restrict__ lds, int rowOfs, int r, int c,
    float rain_v, float gno_v,
    float rr, float evapr, float minhd, float heps, float gravr, float sccr,
    float diss, float depo,
    float& s_io, float& w_io, float& v_io, float& t_out, bool fin)
{
    #pragma clang fp contract(off)
    const float CELLW = 0.390625f;            // 200/512, exact

    float t_c = lds[(r - rowOfs) * WW + c];

    float w = fmaf(rr, rain_v, w_io);

    float dx, dy;
    if      (r == 0)      dx = 0.5f * fmaf(t_c, 1.1f, -t_c);
    else if (r == WW - 1) dx = 0.5f * fmaf(t_c, 0.9f, -t_c);
    else dx = 0.5f * (lds[(r + 1 - rowOfs) * WW + c] - lds[(r - 1 - rowOfs) * WW + c]);
    if      (c == 0)      dy = 0.5f * fmaf(t_c, 1.1f, -t_c);
    else if (c == WW - 1) dy = 0.5f * fmaf(t_c, 0.9f, -t_c);
    else dy = 0.5f * (lds[(r - rowOfs) * WW + c + 1] - lds[(r - rowOfs) * WW + c - 1]);

    float mag = sqrtf(fmaf(dx, dx, dy * dy) + 1e-11f);
    // r18 bit-exact DCE: mag >= sqrt(1e-11) = 3.16e-6 > 1e-10, so
    // factor = relu(1e-10 - mag) == 0, rY unused, den = mag + 0 = mag.
    // fmaf(0, rX, dx) == dx (sign-of-zero flip absorbed downstream).
    float fdx = dx / mag;                     // |fdx| <= 1 + ~3ulp
    float fdy = dy / mag;                     // |fdy| <= 1 + ~3ulp

    float fx  = (float)c + (-fdx);
    float fy  = (float)r + (-fdy);
    float x0f = floorf(fx), y0f = floorf(fy);
    float wx1 = fx - x0f;
    float wy1 = fy - y0f;
    int x0 = (int)x0f, y0 = (int)y0f;
    int x1 = x0 + 1,   y1 = y0 + 1;

    bool vx0 = (x0 >= 0) & (x0 < WW);
    bool vx1 = (x1 >= 0) & (x1 < WW);
    bool vy0 = (y0 >= 0) & (y0 < WW);
    bool vy1 = (y1 >= 0) & (y1 < WW);
    int x0c = min(max(x0, 0), WW - 1), x1c = min(max(x1, 0), WW - 1);
    int y0c = min(max(y0, 0), WW - 1), y1c = min(max(y1, 0), WW - 1);
    int ty0 = y0c - rowOfs, ty1 = y1c - rowOfs;   // in [r-2,r+2]-rowOfs

    float g00 = (vx0 && vy0) ? (lds[ty0 * WW + x0c] - 1.0f) : 0.0f;
    float g10 = (vx1 && vy0) ? (lds[ty0 * WW + x1c] - 1.0f) : 0.0f;
    float g01 = (vx0 && vy1) ? (lds[ty1 * WW + x0c] - 1.0f) : 0.0f;
    float g11 = (vx1 && vy1) ? (lds[ty1 * WW + x1c] - 1.0f) : 0.0f;

    float wx0 = 1.0f - wx1;
    float wy0 = 1.0f - wy1;
    float rowA = fmaf(wx0, g00, wx1 * g10);
    float rowB = fmaf(wx0, g01, wx1 * g11);
    float bil  = fmaf(wy0, rowA, wy1 * rowB);
    float neighbor = bil + 1.0f;

    float hd = t_c - neighbor;

    float v = v_io;
    float s = s_io;

    float hds  = ((hd - heps) > 0.0f) ? 1.0f : 0.0f;  // sign(relu(hd-eps))
    float nhd  = hds * fmaxf(hd, minhd);
    float q1 = nhd / CELLW;
    float q2 = q1 * v;
    float q3 = q2 * w;
    float sdiff = fmaf(-q3, sccr, s);                 // s - sed_cap
    float ftb   = (hd < 0.0f) ? 1.0f : 0.0f;          // relu(sign(-hd))
    float first = fminf(fmaxf(-hd, 0.0f), s);
    float ra = fmaxf(sdiff * depo, 0.0f);
    float rb = fmaxf((-sdiff) * diss, 0.0f);
    float deparg = fmaf(1.0f - ftb, ra - rb, first);
    float dep    = fmaxf(-fmaxf(hd, 0.0f), deparg);

    float s_new = s - dep;
    float t_new = t_c + dep;

    float rn = fmaxf(-fdy, 0.0f);
    float rm = fmaxf(1.0f - fabsf(fdy), 0.0f);
    float rp = fmaxf(fdy, 0.0f);

    float s1 = (c == WW - 1) ? 0.0f : rn * s_new;
    float s3 = (c == 0)      ? 0.0f : rp * s_new;
    s_io = fmaf(rm, s_new, s1) + s3;

    float w1 = (c == WW - 1) ? 0.0f : rn * w;
    float w3 = (c == 0)      ? 0.0f : rp * w;
    float wd = fmaf(rm, w, w1) + w3;
    w_io = wd * (1.0f - evapr);

    v_io = (gravr * hd) / CELLW;

    if (fin) {
        float aa = fmaf(-t_new, 2.0f, 1.0f);          // 1 - t*2 -> fnma
        float bq = 1.0f + aa;
        t_out = fmaxf(bq, 0.0f) - 1.0f;
    } else {
        t_out = t_new;
    }
}

template <bool FIRST, bool FINAL>
__global__ __launch_bounds__(512, 8) void erosion_fused(
    const float* __restrict__ tin, float* __restrict__ tout,
    const float* __restrict__ sed_in, const float* __restrict__ wat_in,
    const float* __restrict__ vel_in,
    float* __restrict__ sed_out, float* __restrict__ wat_out,
    float* __restrict__ vel_out,
    const float* __restrict__ rain0, const float* __restrict__ gno0,
    const float* __restrict__ rain1, const float* __restrict__ gno1,
    const float* __restrict__ s_rain_rate, const float* __restrict__ s_evap,
    const float* __restrict__ s_minhd, const float* __restrict__ s_heps,
    const float* __restrict__ s_grav, const float* __restrict__ s_scc,
    const float* __restrict__ s_diss, const float* __restrict__ s_depo)
{
    #pragma clang fp contract(off)
    __shared__ float A[AR * WW];    // terrain k-1 rows [r0-4, r0+11];
                                    // phase 1 retires slot i -> terrain-k
                                    // row r0-2+i (in-place aliasing)

    const int c   = threadIdx.x;
    const int img = blockIdx.x >> 6;           // 64 tiles per image
    const int r0  = (blockIdx.x & 63) * HH;
    const float* tb = tin + (size_t)img * NPIX;

    float rr    = fmaxf(s_rain_rate[0], 0.0f);
    float evapr = fmaxf(s_evap[0], 0.0f);
    float minhd = s_minhd[0];
    float heps  = s_heps[0];
    float gravr = fmaxf(s_grav[0], 0.0f);
    float sccr  = fmaxf(s_scc[0], 0.0f);
    float diss  = s_diss[0];
    float depo  = s_depo[0];

    // ---- stage terrain k-1 rows [r0-4, r0+11] (float4; transform if FIRST)
    // 4 groups of 128 threads; group rg loads rows {rg, rg+4, rg+8, rg+12};
    // 128 float4 = full 512-col row each. Exact cover of tile rows 0..15.
    {
        const int rg = c >> 7;               // 0..3
        const int c4 = (c & 127) << 2;       // column start (float4 aligned)
        #pragma unroll
        for (int j = 0; j < 4; ++j) {
            int ridx = j * 4 + rg;           // 0..15, each exactly once
            int y = r0 - 4 + ridx;
            if (y >= 0 && y < WW) {
                float4 v = *reinterpret_cast<const float4*>(tb + y * WW + c4);
                if (FIRST) {
                    v.x = (1.0f - v.x) / 2.0f;
                    v.y = (1.0f - v.y) / 2.0f;
                    v.z = (1.0f - v.z) / 2.0f;
                    v.w = (1.0f - v.w) / 2.0f;
                }
                *reinterpret_cast<float4*>(&A[ridx * WW + c4]) = v;
            }
        }
    }
    __syncthreads();

    // ---- phase 1: step k over extended rows [r0-2, r0+9], PAIRED +
    // in-place retire. Row x = r0-2+i reads A slots i..i+4 only (incl.
    // clamps); after the pair's barrier, slots i,i+1 are dead -> receive
    // terrain-k rows. s/w/v read from dbuf set-IN (previous dispatch only).
    float sK[HH], wK[HH], vK[HH];
    #pragma unroll
    for (int ii = 0; ii < BR; ii += 2) {
        float tn0 = 0.0f, tn1 = 0.0f;
        float sa = 0.0f, wa = 0.0f, va = 0.0f;
        float sb = 0.0f, wb = 0.0f, vb = 0.0f;
        {
            int x = r0 - 2 + ii;
            if (x >= 0 && x < WW) {          // uniform across block
                if (!FIRST) {
                    int g = img * NPIX + x * WW + c;
                    sa = sed_in[g]; wa = wat_in[g]; va = vel_in[g];
                }
                cell_math(A, r0 - 4, x, c, rain0[x * WW + c], gno0[x * WW + c],
                          rr, evapr, minhd, heps, gravr, sccr, diss, depo,
                          sa, wa, va, tn0, false);
            }
        }
        {
            int x = r0 - 1 + ii;
            if (x >= 0 && x < WW) {
                if (!FIRST) {
                    int g = img * NPIX + x * WW + c;
                    sb = sed_in[g]; wb = wat_in[g]; vb = vel_in[g];
                }
                cell_math(A, r0 - 4, x, c, rain0[x * WW + c], gno0[x * WW + c],
                          rr, evapr, minhd, heps, gravr, sccr, diss, depo,
                          sb, wb, vb, tn1, false);
            }
        }
        __syncthreads();   // all reads of slots ii, ii+1 complete block-wide
        {
            int x = r0 - 2 + ii;
            if (x >= 0 && x < WW) {
                A[ii * WW + c] = tn0;
                if (ii >= 2 && ii <= HH + 1) {
                    sK[ii - 2] = sa; wK[ii - 2] = wa; vK[ii - 2] = va;
                }
            }
        }
        {
            int i1 = ii + 1, x = r0 - 1 + ii;
            if (x >= 0 && x < WW) {
                A[i1 * WW + c] = tn1;
                if (i1 >= 2 && i1 <= HH + 1) {
                    sK[i1 - 2] = sb; wK[i1 - 2] = wb; vK[i1 - 2] = vb;
                }
            }
        }
    }
    __syncthreads();       // terrain-k slots 0..11 visible block-wide

    // ---- phase 2: step k+1 over owned rows [r0, r0+7]; terrain k lives in
    // A slots 0..11 with rowOfs r0-2 (slot j = row r0-2+j). Row x reads
    // slots j..j+4 (j = x-r0) subset of 0..11; stale slots 12..15 (and 0..1
    // at r0=0) are clamped away.
    #pragma unroll
    for (int j = 0; j < HH; ++j) {
        int x = r0 + j;
        float s0 = sK[j], w0 = wK[j], v0 = vK[j];
        float tn;
        cell_math(A, r0 - 2, x, c, rain1[x * WW + c], gno1[x * WW + c],
                  rr, evapr, minhd, heps, gravr, sccr, diss, depo,
                  s0, w0, v0, tn, FINAL);
        int g = img * NPIX + x * WW + c;
        tout[g] = tn;
        if (!FINAL) { sed_out[g] = s0; wat_out[g] = w0; vel_out[g] = v0; }
    }
}

extern "C" void kernel_launch(void* const* d_in, const int* in_sizes, int n_in,
                              void* d_out, int out_size, void* d_ws, size_t ws_size,
                              hipStream_t stream) {
    const float* in_terr    = (const float*)d_in[0];
    const float* rain_all   = (const float*)d_in[1];  // (1,10,W,W)
    const float* gnoise_all = (const float*)d_in[2];  // (1,10,W,W)
    const float* p_rr       = (const float*)d_in[3];
    const float* p_evap     = (const float*)d_in[4];
    const float* p_minhd    = (const float*)d_in[5];
    const float* p_heps     = (const float*)d_in[6];
    const float* p_grav     = (const float*)d_in[7];
    const float* p_scc      = (const float*)d_in[8];
    const float* p_diss     = (const float*)d_in[9];
    const float* p_depo     = (const float*)d_in[10];

    float* T0  = (float*)d_out;          // final output
    float* ws  = (float*)d_ws;
    float* T1  = ws;
    float* T2  = ws + (size_t)NTOT;
    float* sA  = ws + (size_t)2 * NTOT;
    float* wA  = ws + (size_t)3 * NTOT;
    float* vA  = ws + (size_t)4 * NTOT;
    float* sB, * wB, * vB;
    if (ws_size >= (size_t)8 * NTOT * sizeof(float)) {
        sB = ws + (size_t)5 * NTOT;
        wB = ws + (size_t)6 * NTOT;
        vB = ws + (size_t)7 * NTOT;
    } else {
        // insufficient workspace: fall back to single-buffer (r14 behavior)
        sB = sA; wB = wA; vB = vA;
    }

    dim3 grid(NBLK), block(512);
    #define RN(k) (rain_all   + (size_t)(k) * NPIX)
    #define GN(k) (gnoise_all + (size_t)(k) * NPIX)
    #define SCAL p_rr, p_evap, p_minhd, p_heps, p_grav, p_scc, p_diss, p_depo

    // steps 0+1: in_terr -> T1; s/w/v: (zeros) -> set A
    erosion_fused<true, false><<<grid, block, 0, stream>>>(
        in_terr, T1, sA, wA, vA, sA, wA, vA, RN(0), GN(0), RN(1), GN(1), SCAL);
    // steps 2+3: T1 -> T2; s/w/v: A -> B
    erosion_fused<false, false><<<grid, block, 0, stream>>>(
        T1, T2, sA, wA, vA, sB, wB, vB, RN(2), GN(2), RN(3), GN(3), SCAL);
    // steps 4+5: T2 -> T1; s/w/v: B -> A
    erosion_fused<false, false><<<grid, block, 0, stream>>>(
        T2, T1, sB, wB, vB, sA, wA, vA, RN(4), GN(4), RN(5), GN(5), SCAL);
    // steps 6+7: T1 -> T2; s/w/v: A -> B
    erosion_fused<false, false><<<grid, block, 0, stream>>>(
        T1, T2, sA, wA, vA, sB, wB, vB, RN(6), GN(6), RN(7), GN(7), SCAL);
    // steps 8+9: T2 -> T0 (= d_out), final transform; s/w/v: B -> (dead)
    erosion_fused<false, true><<<grid, block, 0, stream>>>(
        T2, T0, sB, wB, vB, sA, wA, vA, RN(8), GN(8), RN(9), GN(9), SCAL);

    #undef RN
    #undef GN
    #undef SCAL
}